// Round 3
// baseline (356.376 us; speedup 1.0000x reference)
//
#include <hip/hip_runtime.h>
#include <math.h>

// Problem constants (16 x 1 x 1024 x 1024 fp32 pred/mask -> scalar fp32 loss)
#define BATCH 16
#define H 1024
#define W 1024
#define TILE 64
#define HALO 15                 // max pad = 31/2
#define HREG (TILE + 2 * HALO)  // 94: halo region side
#define SROWS 97                // rows 0..96; rows 95,96 zero-padded so col-scan unrolls 12x8
#define SCOLS 97                // stride 97 % 32 == 1 -> both scans hit all 32 banks (conflict-free)

// d_ws accumulator layout: acc[b*5 + {0:weit,1:weit*bce,2:inter,3:union,4:mae}]
#define ACC_N (BATCH * 5)

__global__ __launch_bounds__(256)
void adaptive_loss_main(const float* __restrict__ pred,
                        const float* __restrict__ mask,
                        float* __restrict__ acc) {
    __shared__ float sat[SROWS * SCOLS];
    __shared__ float red[4][5];

    const int tid = threadIdx.x;
    const int b   = blockIdx.z;
    const int ty0 = blockIdx.y * TILE;
    const int tx0 = blockIdx.x * TILE;
    const float* mimg = mask + (size_t)b * H * W;
    const float* pimg = pred + (size_t)b * H * W;

    // ---- Hoisted phase-3 global loads: issue now, HBM latency resolves during the scans ----
    float4 m4[4], p4[4];
    #pragma unroll
    for (int i = 0; i < 4; ++i) {
        int y  = (tid >> 4) + 16 * i;
        int x4 = (tid & 15) << 2;
        size_t off = (size_t)(ty0 + y) * W + (tx0 + x4);
        m4[i] = *(const float4*)(mimg + off);
        p4[i] = *(const float4*)(pimg + off);
    }

    // ---- Phase 0: zero-padded halo into sat[1..94][1..94]; borders (incl rows/cols 95,96) = 0 ----
    for (int idx = tid; idx < SROWS * SCOLS; idx += 256) {
        int r = idx / SCOLS;
        int c = idx - r * SCOLS;
        float v = 0.0f;
        if (r >= 1 && r <= HREG && c >= 1 && c <= HREG) {
            int gy = ty0 - HALO + (r - 1);
            int gx = tx0 - HALO + (c - 1);
            if (gy >= 0 && gy < H && gx >= 0 && gx < W)
                v = mimg[gy * W + gx];
        }
        sat[idx] = v;
    }
    __syncthreads();

    // ---- Phase 1: row prefix, thread per row, ILP-8 (12 iters of 8 indep reads + add chain) ----
    if (tid < 96) {
        float carry = 0.0f;
        const int base = (tid + 1) * SCOLS;
        #pragma unroll
        for (int it = 0; it < 12; ++it) {
            const int c0 = 1 + 8 * it;
            float v[8];
            #pragma unroll
            for (int i = 0; i < 8; ++i) v[i] = sat[base + c0 + i];
            #pragma unroll
            for (int i = 0; i < 8; ++i) { carry += v[i]; v[i] = carry; }
            #pragma unroll
            for (int i = 0; i < 8; ++i) sat[base + c0 + i] = v[i];
        }
    }
    __syncthreads();

    // ---- Phase 2: col prefix, thread per col, ILP-8 ----
    if (tid < 96) {
        float carry = 0.0f;
        const int c = tid + 1;
        #pragma unroll
        for (int it = 0; it < 12; ++it) {
            const int r0 = 1 + 8 * it;
            float v[8];
            #pragma unroll
            for (int i = 0; i < 8; ++i) v[i] = sat[(r0 + i) * SCOLS + c];
            #pragma unroll
            for (int i = 0; i < 8; ++i) { carry += v[i]; v[i] = carry; }
            #pragma unroll
            for (int i = 0; i < 8; ++i) sat[(r0 + i) * SCOLS + c] = v[i];
        }
    }
    __syncthreads();

    // ---- Phase 3: per-pixel fused compute from the SAT ----
    float s_w = 0.0f, s_wb = 0.0f, s_in = 0.0f, s_un = 0.0f, s_mae = 0.0f;

    const int pp[3]    = {1, 7, 15};
    const float inv[3] = {1.0f / 9.0f, 1.0f / 225.0f, 1.0f / 961.0f};

    #pragma unroll
    for (int i = 0; i < 4; ++i) {
        int y  = (tid >> 4) + 16 * i;
        int x4 = (tid & 15) << 2;
        const int rc = y + HALO + 1;

        #pragma unroll
        for (int q = 0; q < 4; ++q) {
            float m  = (&m4[i].x)[q];
            float pr = (&p4[i].x)[q];
            int cc = x4 + q + HALO + 1;

            float w = 0.0f;
            #pragma unroll
            for (int j = 0; j < 3; ++j) {
                int r2 = (rc + pp[j]) * SCOLS, r1 = (rc - pp[j] - 1) * SCOLS;
                int c2 = cc + pp[j],           c1 = cc - pp[j] - 1;
                float s = sat[r2 + c2] - sat[r1 + c2]
                        - sat[r2 + c1] + sat[r1 + c1];
                w += fabsf(s * inv[j] - m);
            }
            float weit = 1.0f + 5.0f * w;
            float t    = __expf(-fabsf(pr));                 // shared by bce & sigmoid
            float bce  = fmaxf(pr, 0.0f) - pr * m + __logf(1.0f + t);
            float u    = __builtin_amdgcn_rcpf(1.0f + t);    // 1/(1+e^-|pr|)
            float sig  = (pr >= 0.0f) ? u : 1.0f - u;

            s_w   += weit;
            s_wb  += weit * bce;
            s_in  += sig * m * weit;
            s_un  += (sig + m) * weit;
            s_mae += fabsf(sig - m);
        }
    }

    // ---- Phase 4: block reduction (wave shuffle, then LDS across 4 waves) ----
    #pragma unroll
    for (int off = 32; off > 0; off >>= 1) {
        s_w   += __shfl_down(s_w,   off);
        s_wb  += __shfl_down(s_wb,  off);
        s_in  += __shfl_down(s_in,  off);
        s_un  += __shfl_down(s_un,  off);
        s_mae += __shfl_down(s_mae, off);
    }
    int wave = tid >> 6, lane = tid & 63;
    if (lane == 0) {
        red[wave][0] = s_w;  red[wave][1] = s_wb; red[wave][2] = s_in;
        red[wave][3] = s_un; red[wave][4] = s_mae;
    }
    __syncthreads();
    if (tid == 0) {
        float r0 = 0, r1 = 0, r2 = 0, r3 = 0, r4 = 0;
        #pragma unroll
        for (int wv = 0; wv < 4; ++wv) {
            r0 += red[wv][0]; r1 += red[wv][1]; r2 += red[wv][2];
            r3 += red[wv][3]; r4 += red[wv][4];
        }
        atomicAdd(&acc[b * 5 + 0], r0);
        atomicAdd(&acc[b * 5 + 1], r1);
        atomicAdd(&acc[b * 5 + 2], r2);
        atomicAdd(&acc[b * 5 + 3], r3);
        atomicAdd(&acc[b * 5 + 4], r4);
    }
}

__global__ void adaptive_loss_finalize(const float* __restrict__ acc,
                                       float* __restrict__ out) {
    if (threadIdx.x == 0 && blockIdx.x == 0) {
        float smae = 0.0f;
        for (int b = 0; b < BATCH; ++b) smae += acc[b * 5 + 4];
        float mae = smae / (float)((size_t)BATCH * H * W);
        float tot = 0.0f;
        for (int b = 0; b < BATCH; ++b) {
            float Sw  = acc[b * 5 + 0];
            float Swb = acc[b * 5 + 1];
            float Si  = acc[b * 5 + 2];
            float Su  = acc[b * 5 + 3];
            float wbce = Swb / Sw;
            float wiou = 1.0f - (Si + 1.0f) / (Su - Si + 1.0f);
            float wmae = mae * Sw / (Sw - (float)(H * W));
            tot += 0.7f * (wbce + wiou + wmae);
        }
        out[0] = tot / (float)BATCH;
    }
}

extern "C" void kernel_launch(void* const* d_in, const int* in_sizes, int n_in,
                              void* d_out, int out_size, void* d_ws, size_t ws_size,
                              hipStream_t stream) {
    const float* pred = (const float*)d_in[0];
    const float* mask = (const float*)d_in[1];
    float* acc = (float*)d_ws;

    hipMemsetAsync(acc, 0, ACC_N * sizeof(float), stream);

    dim3 grid(W / TILE, H / TILE, BATCH);
    adaptive_loss_main<<<grid, 256, 0, stream>>>(pred, mask, acc);
    adaptive_loss_finalize<<<1, 64, 0, stream>>>(acc, (float*)d_out);
}

// Round 4
// 311.925 us; speedup vs baseline: 1.1425x; 1.1425x over previous
//
#include <hip/hip_runtime.h>
#include <math.h>

// Problem constants (16 x 1 x 1024 x 1024 fp32 pred/mask -> scalar fp32 loss)
#define BATCH 16
#define H 1024
#define W 1024
#define TILE 64
#define HALO 15                 // max pad = 31/2
#define HREG (TILE + 2 * HALO)  // 94: halo region side
#define SROWS 97                // rows 0..96; rows 95,96 zero-padded so col-scan unrolls 12x8
#define SCOLS 97                // stride 97 % 32 == 1 -> both scans hit all 32 banks (conflict-free)

// d_ws accumulator layout: acc[b*5 + {0:weit,1:weit*bce,2:inter,3:union,4:mae}]
#define ACC_N (BATCH * 5)

__global__ __launch_bounds__(256)
void adaptive_loss_main(const float* __restrict__ pred,
                        const float* __restrict__ mask,
                        float* __restrict__ acc) {
    __shared__ float sat[SROWS * SCOLS];
    __shared__ float red[4][5];

    const int tid = threadIdx.x;
    const int b   = blockIdx.z;
    const int ty0 = blockIdx.y * TILE;
    const int tx0 = blockIdx.x * TILE;
    const float* mimg = mask + (size_t)b * H * W;
    const float* pimg = pred + (size_t)b * H * W;

    // ---- Phase 0: zero-padded halo into sat[1..94][1..94]; borders (incl rows/cols 95,96) = 0 ----
    // NOTE: no hoisted pred/mask loads here — R3 showed far-ahead loads held across this
    // load->ds_write loop poison the waitcnt queue and cost ~40us. Loads live in phase 3.
    for (int idx = tid; idx < SROWS * SCOLS; idx += 256) {
        int r = idx / SCOLS;
        int c = idx - r * SCOLS;
        float v = 0.0f;
        if (r >= 1 && r <= HREG && c >= 1 && c <= HREG) {
            int gy = ty0 - HALO + (r - 1);
            int gx = tx0 - HALO + (c - 1);
            if (gy >= 0 && gy < H && gx >= 0 && gx < W)
                v = mimg[gy * W + gx];
        }
        sat[idx] = v;
    }
    __syncthreads();

    // ---- Phase 1: row prefix, thread per row, ILP-8 (12 iters of 8 indep reads + add chain) ----
    if (tid < 96) {
        float carry = 0.0f;
        const int base = (tid + 1) * SCOLS;
        #pragma unroll
        for (int it = 0; it < 12; ++it) {
            const int c0 = 1 + 8 * it;
            float v[8];
            #pragma unroll
            for (int i = 0; i < 8; ++i) v[i] = sat[base + c0 + i];
            #pragma unroll
            for (int i = 0; i < 8; ++i) { carry += v[i]; v[i] = carry; }
            #pragma unroll
            for (int i = 0; i < 8; ++i) sat[base + c0 + i] = v[i];
        }
    }
    __syncthreads();

    // ---- Phase 2: col prefix, thread per col, ILP-8 ----
    if (tid < 96) {
        float carry = 0.0f;
        const int c = tid + 1;
        #pragma unroll
        for (int it = 0; it < 12; ++it) {
            const int r0 = 1 + 8 * it;
            float v[8];
            #pragma unroll
            for (int i = 0; i < 8; ++i) v[i] = sat[(r0 + i) * SCOLS + c];
            #pragma unroll
            for (int i = 0; i < 8; ++i) { carry += v[i]; v[i] = carry; }
            #pragma unroll
            for (int i = 0; i < 8; ++i) sat[(r0 + i) * SCOLS + c] = v[i];
        }
    }
    __syncthreads();

    // ---- Phase 3: per-pixel fused compute, float4 global loads (issued here, not hoisted) ----
    float s_w = 0.0f, s_wb = 0.0f, s_in = 0.0f, s_un = 0.0f, s_mae = 0.0f;

    const int pp[3]    = {1, 7, 15};
    const float inv[3] = {1.0f / 9.0f, 1.0f / 225.0f, 1.0f / 961.0f};

    #pragma unroll
    for (int i = 0; i < 4; ++i) {
        int y  = (tid >> 4) + 16 * i;   // 0..63
        int x4 = (tid & 15) << 2;       // 0,4,...,60
        int gy = ty0 + y, gx = tx0 + x4;
        const float4 m4 = *(const float4*)(mimg + (size_t)gy * W + gx);
        const float4 p4 = *(const float4*)(pimg + (size_t)gy * W + gx);
        const int rc = y + HALO + 1;

        #pragma unroll
        for (int q = 0; q < 4; ++q) {
            float m  = (&m4.x)[q];
            float pr = (&p4.x)[q];
            int cc = x4 + q + HALO + 1;

            float w = 0.0f;
            #pragma unroll
            for (int j = 0; j < 3; ++j) {
                int r2 = (rc + pp[j]) * SCOLS, r1 = (rc - pp[j] - 1) * SCOLS;
                int c2 = cc + pp[j],           c1 = cc - pp[j] - 1;
                float s = sat[r2 + c2] - sat[r1 + c2]
                        - sat[r2 + c1] + sat[r1 + c1];
                w += fabsf(s * inv[j] - m);
            }
            float weit = 1.0f + 5.0f * w;
            float t    = __expf(-fabsf(pr));                 // shared by bce & sigmoid
            float bce  = fmaxf(pr, 0.0f) - pr * m + __logf(1.0f + t);
            float u    = __builtin_amdgcn_rcpf(1.0f + t);    // 1/(1+e^-|pr|)
            float sig  = (pr >= 0.0f) ? u : 1.0f - u;

            s_w   += weit;
            s_wb  += weit * bce;
            s_in  += sig * m * weit;
            s_un  += (sig + m) * weit;
            s_mae += fabsf(sig - m);
        }
    }

    // ---- Phase 4: block reduction (wave shuffle, then LDS across 4 waves) ----
    #pragma unroll
    for (int off = 32; off > 0; off >>= 1) {
        s_w   += __shfl_down(s_w,   off);
        s_wb  += __shfl_down(s_wb,  off);
        s_in  += __shfl_down(s_in,  off);
        s_un  += __shfl_down(s_un,  off);
        s_mae += __shfl_down(s_mae, off);
    }
    int wave = tid >> 6, lane = tid & 63;
    if (lane == 0) {
        red[wave][0] = s_w;  red[wave][1] = s_wb; red[wave][2] = s_in;
        red[wave][3] = s_un; red[wave][4] = s_mae;
    }
    __syncthreads();
    if (tid == 0) {
        float r0 = 0, r1 = 0, r2 = 0, r3 = 0, r4 = 0;
        #pragma unroll
        for (int wv = 0; wv < 4; ++wv) {
            r0 += red[wv][0]; r1 += red[wv][1]; r2 += red[wv][2];
            r3 += red[wv][3]; r4 += red[wv][4];
        }
        atomicAdd(&acc[b * 5 + 0], r0);
        atomicAdd(&acc[b * 5 + 1], r1);
        atomicAdd(&acc[b * 5 + 2], r2);
        atomicAdd(&acc[b * 5 + 3], r3);
        atomicAdd(&acc[b * 5 + 4], r4);
    }
}

__global__ void adaptive_loss_finalize(const float* __restrict__ acc,
                                       float* __restrict__ out) {
    if (threadIdx.x == 0 && blockIdx.x == 0) {
        float smae = 0.0f;
        for (int b = 0; b < BATCH; ++b) smae += acc[b * 5 + 4];
        float mae = smae / (float)((size_t)BATCH * H * W);
        float tot = 0.0f;
        for (int b = 0; b < BATCH; ++b) {
            float Sw  = acc[b * 5 + 0];
            float Swb = acc[b * 5 + 1];
            float Si  = acc[b * 5 + 2];
            float Su  = acc[b * 5 + 3];
            float wbce = Swb / Sw;
            float wiou = 1.0f - (Si + 1.0f) / (Su - Si + 1.0f);
            float wmae = mae * Sw / (Sw - (float)(H * W));
            tot += 0.7f * (wbce + wiou + wmae);
        }
        out[0] = tot / (float)BATCH;
    }
}

extern "C" void kernel_launch(void* const* d_in, const int* in_sizes, int n_in,
                              void* d_out, int out_size, void* d_ws, size_t ws_size,
                              hipStream_t stream) {
    const float* pred = (const float*)d_in[0];
    const float* mask = (const float*)d_in[1];
    float* acc = (float*)d_ws;

    hipMemsetAsync(acc, 0, ACC_N * sizeof(float), stream);

    dim3 grid(W / TILE, H / TILE, BATCH);
    adaptive_loss_main<<<grid, 256, 0, stream>>>(pred, mask, acc);
    adaptive_loss_finalize<<<1, 64, 0, stream>>>(acc, (float*)d_out);
}

// Round 5
// 265.236 us; speedup vs baseline: 1.3436x; 1.1760x over previous
//
#include <hip/hip_runtime.h>
#include <math.h>

// Problem constants (16 x 1 x 1024 x 1024 fp32 pred/mask -> scalar fp32 loss)
#define BATCH 16
#define H 1024
#define W 1024
#define TILE 64
// Halo layout: halo row hr in [0,96) <-> gy = ty0 - 16 + hr; same for cols.
// Pixel (y,x) of tile <-> halo (y+16, x+16). Windows (p<=15) touch hr,hc in [0,95).
// SAT = inclusive 2D prefix over the 96x96 halo; box = S[r2][c2]-S[r1][c2]-S[r2][c1]+S[r1][c1]
// with r2=y+16+p, r1=y+16-p-1 >= 0 (left halo 16 gives the -1 room; no zero border needed).
#define HDIM 96
#define SCOLS 97   // stride 97 % 32 == 1 -> row walks, col walks, and 2D-linear walks all bank-perfect

// d_ws accumulator layout: acc[b*5 + {0:weit,1:weit*bce,2:inter,3:union,4:mae}]
#define ACC_N (BATCH * 5)

__global__ __launch_bounds__(512, 8)   // 8 waves/EU -> VGPR cap 64 -> 4 blocks/CU = 32 waves/CU
void adaptive_loss_main(const float* __restrict__ pred,
                        const float* __restrict__ mask,
                        float* __restrict__ acc) {
    __shared__ float sat[HDIM * SCOLS];
    __shared__ float red[8][5];

    const int tid = threadIdx.x;
    const int b   = blockIdx.z;
    const int ty0 = blockIdx.y * TILE;
    const int tx0 = blockIdx.x * TILE;
    const float* mimg = mask + (size_t)b * H * W;
    const float* pimg = pred + (size_t)b * H * W;

    // ---- Phase 0: zero-padded 96x96 halo -> LDS. Incremental (r,c) walk: 9216/512 = 18 iters,
    //      no per-iteration division. Lanes walk consecutive cells -> coalesced global reads and
    //      bank-perfect LDS writes (stride 97). Batched x3 so loads pipeline ahead of writes.
    {
        int r = tid / 96;          // 0..5
        int c = tid - r * 96;
        #pragma unroll
        for (int ot = 0; ot < 6; ++ot) {
            float v[3];
            int   a[3];
            #pragma unroll
            for (int j = 0; j < 3; ++j) {
                int gy = ty0 - 16 + r;
                int gx = tx0 - 16 + c;
                a[j] = r * SCOLS + c;
                v[j] = (gy >= 0 && gy < H && gx >= 0 && gx < W)
                         ? mimg[gy * W + gx] : 0.0f;
                r += 5; c += 32;
                if (c >= 96) { c -= 96; r += 1; }
            }
            #pragma unroll
            for (int j = 0; j < 3; ++j) sat[a[j]] = v[j];
        }
    }
    __syncthreads();

    // ---- Phase 1: row prefix, thread per row (96 rows), ILP-8: 12 chunks of 8 ----
    if (tid < HDIM) {
        float carry = 0.0f;
        const int base = tid * SCOLS;
        #pragma unroll
        for (int it = 0; it < 12; ++it) {
            const int c0 = 8 * it;
            float v[8];
            #pragma unroll
            for (int i = 0; i < 8; ++i) v[i] = sat[base + c0 + i];
            #pragma unroll
            for (int i = 0; i < 8; ++i) { carry += v[i]; v[i] = carry; }
            #pragma unroll
            for (int i = 0; i < 8; ++i) sat[base + c0 + i] = v[i];
        }
    }
    __syncthreads();

    // ---- Phase 2: col prefix, thread per col (96 cols), ILP-8 ----
    if (tid < HDIM) {
        float carry = 0.0f;
        const int c = tid;
        #pragma unroll
        for (int it = 0; it < 12; ++it) {
            const int r0 = 8 * it;
            float v[8];
            #pragma unroll
            for (int i = 0; i < 8; ++i) v[i] = sat[(r0 + i) * SCOLS + c];
            #pragma unroll
            for (int i = 0; i < 8; ++i) { carry += v[i]; v[i] = carry; }
            #pragma unroll
            for (int i = 0; i < 8; ++i) sat[(r0 + i) * SCOLS + c] = v[i];
        }
    }
    __syncthreads();

    // ---- Phase 3: per-pixel fused compute, float4 global loads (NOT hoisted — R3 lesson) ----
    float s_w = 0.0f, s_wb = 0.0f, s_in = 0.0f, s_un = 0.0f, s_mae = 0.0f;

    const int pp[3]    = {1, 7, 15};
    const float inv[3] = {1.0f / 9.0f, 1.0f / 225.0f, 1.0f / 961.0f};

    #pragma unroll
    for (int i = 0; i < 2; ++i) {
        int y  = (tid >> 4) + 32 * i;   // 0..63
        int x4 = (tid & 15) << 2;       // 0,4,...,60
        int gy = ty0 + y, gx = tx0 + x4;
        const float4 m4 = *(const float4*)(mimg + (size_t)gy * W + gx);
        const float4 p4 = *(const float4*)(pimg + (size_t)gy * W + gx);
        const int rc = y + 16;

        #pragma unroll
        for (int q = 0; q < 4; ++q) {
            float m  = (&m4.x)[q];
            float pr = (&p4.x)[q];
            int cc = x4 + q + 16;

            float w = 0.0f;
            #pragma unroll
            for (int j = 0; j < 3; ++j) {
                int r2 = (rc + pp[j]) * SCOLS, r1 = (rc - pp[j] - 1) * SCOLS;
                int c2 = cc + pp[j],           c1 = cc - pp[j] - 1;
                float s = sat[r2 + c2] - sat[r1 + c2]
                        - sat[r2 + c1] + sat[r1 + c1];
                w += fabsf(s * inv[j] - m);
            }
            float weit = 1.0f + 5.0f * w;
            float t    = __expf(-fabsf(pr));                 // shared by bce & sigmoid
            float bce  = fmaxf(pr, 0.0f) - pr * m + __logf(1.0f + t);
            float u    = __builtin_amdgcn_rcpf(1.0f + t);    // 1/(1+e^-|pr|)
            float sig  = (pr >= 0.0f) ? u : 1.0f - u;

            s_w   += weit;
            s_wb  += weit * bce;
            s_in  += sig * m * weit;
            s_un  += (sig + m) * weit;
            s_mae += fabsf(sig - m);
        }
    }

    // ---- Phase 4: block reduction (wave shuffle, then LDS across 8 waves) ----
    #pragma unroll
    for (int off = 32; off > 0; off >>= 1) {
        s_w   += __shfl_down(s_w,   off);
        s_wb  += __shfl_down(s_wb,  off);
        s_in  += __shfl_down(s_in,  off);
        s_un  += __shfl_down(s_un,  off);
        s_mae += __shfl_down(s_mae, off);
    }
    int wave = tid >> 6, lane = tid & 63;
    if (lane == 0) {
        red[wave][0] = s_w;  red[wave][1] = s_wb; red[wave][2] = s_in;
        red[wave][3] = s_un; red[wave][4] = s_mae;
    }
    __syncthreads();
    if (tid == 0) {
        float r0 = 0, r1 = 0, r2 = 0, r3 = 0, r4 = 0;
        #pragma unroll
        for (int wv = 0; wv < 8; ++wv) {
            r0 += red[wv][0]; r1 += red[wv][1]; r2 += red[wv][2];
            r3 += red[wv][3]; r4 += red[wv][4];
        }
        atomicAdd(&acc[b * 5 + 0], r0);
        atomicAdd(&acc[b * 5 + 1], r1);
        atomicAdd(&acc[b * 5 + 2], r2);
        atomicAdd(&acc[b * 5 + 3], r3);
        atomicAdd(&acc[b * 5 + 4], r4);
    }
}

__global__ void adaptive_loss_finalize(const float* __restrict__ acc,
                                       float* __restrict__ out) {
    if (threadIdx.x == 0 && blockIdx.x == 0) {
        float smae = 0.0f;
        for (int b = 0; b < BATCH; ++b) smae += acc[b * 5 + 4];
        float mae = smae / (float)((size_t)BATCH * H * W);
        float tot = 0.0f;
        for (int b = 0; b < BATCH; ++b) {
            float Sw  = acc[b * 5 + 0];
            float Swb = acc[b * 5 + 1];
            float Si  = acc[b * 5 + 2];
            float Su  = acc[b * 5 + 3];
            float wbce = Swb / Sw;
            float wiou = 1.0f - (Si + 1.0f) / (Su - Si + 1.0f);
            float wmae = mae * Sw / (Sw - (float)(H * W));
            tot += 0.7f * (wbce + wiou + wmae);
        }
        out[0] = tot / (float)BATCH;
    }
}

extern "C" void kernel_launch(void* const* d_in, const int* in_sizes, int n_in,
                              void* d_out, int out_size, void* d_ws, size_t ws_size,
                              hipStream_t stream) {
    const float* pred = (const float*)d_in[0];
    const float* mask = (const float*)d_in[1];
    float* acc = (float*)d_ws;

    hipMemsetAsync(acc, 0, ACC_N * sizeof(float), stream);

    dim3 grid(W / TILE, H / TILE, BATCH);
    adaptive_loss_main<<<grid, 512, 0, stream>>>(pred, mask, acc);
    adaptive_loss_finalize<<<1, 64, 0, stream>>>(acc, (float*)d_out);
}

// Round 6
// 261.531 us; speedup vs baseline: 1.3627x; 1.0142x over previous
//
#include <hip/hip_runtime.h>
#include <math.h>

// Problem constants (16 x 1 x 1024 x 1024 fp32 pred/mask -> scalar fp32 loss)
#define BATCH 16
#define H 1024
#define W 1024
#define TILE 64
// Halo layout: halo row hr in [0,96) <-> gy = ty0 - 16 + hr; same for cols.
// Pixel (y,x) of tile <-> halo (y+16, x+16). Windows (p<=15) touch hr,hc in [0,95).
// SAT = inclusive 2D prefix over the 96x96 halo; box = S[r2][c2]-S[r1][c2]-S[r2][c1]+S[r1][c1].
#define HDIM 96
#define SCOLS 97   // stride 97 % 32 == 1 -> scans and lookups land 2-way/bank max (free, m136)
#define SEG  24    // scan segment length: 4 threads per 96-line

// d_ws accumulator layout: acc[b*5 + {0:weit,1:weit*bce,2:inter,3:union,4:mae}]
#define ACC_N (BATCH * 5)

__global__ __launch_bounds__(512, 8)   // 8 waves/EU; LDS caps us at 4 blocks/CU = 32 waves/CU
void adaptive_loss_main(const float* __restrict__ pred,
                        const float* __restrict__ mask,
                        float* __restrict__ acc) {
    __shared__ float sat[HDIM * SCOLS];
    __shared__ float red[8][5];

    const int tid = threadIdx.x;
    const int b   = blockIdx.z;
    const int ty0 = blockIdx.y * TILE;
    const int tx0 = blockIdx.x * TILE;
    const float* mimg = mask + (size_t)b * H * W;
    const float* pimg = pred + (size_t)b * H * W;

    // ---- Phase 0: zero-padded 96x96 halo -> LDS (coalesced, incremental r/c walk) ----
    {
        int r = tid / 96;          // 0..5
        int c = tid - r * 96;
        #pragma unroll
        for (int ot = 0; ot < 6; ++ot) {
            float v[3];
            int   a[3];
            #pragma unroll
            for (int j = 0; j < 3; ++j) {
                int gy = ty0 - 16 + r;
                int gx = tx0 - 16 + c;
                a[j] = r * SCOLS + c;
                v[j] = (gy >= 0 && gy < H && gx >= 0 && gx < W)
                         ? mimg[gy * W + gx] : 0.0f;
                r += 5; c += 32;
                if (c >= 96) { c -= 96; r += 1; }
            }
            #pragma unroll
            for (int j = 0; j < 3; ++j) sat[a[j]] = v[j];
        }
    }
    __syncthreads();

    // ---- Phase 1: row prefix. 4 threads per row (384 active = 6 full waves).
    //      Each: 24 independent reads, 24-add reg chain, in-wave shfl scan of the
    //      4 segment totals (adjacent lanes, no LDS/barrier), offset, write back. ----
    if (tid < 4 * HDIM) {
        const int row = tid >> 2, seg = tid & 3;
        const int base = row * SCOLS + seg * SEG;
        float v[SEG];
        #pragma unroll
        for (int i = 0; i < SEG; ++i) v[i] = sat[base + i];
        #pragma unroll
        for (int i = 1; i < SEG; ++i) v[i] += v[i - 1];
        float tot = v[SEG - 1];
        float inc = tot;
        float t1 = __shfl_up(inc, 1); if (seg >= 1) inc += t1;
        float t2 = __shfl_up(inc, 2); if (seg >= 2) inc += t2;
        const float off = inc - tot;   // exclusive prefix of segment totals
        #pragma unroll
        for (int i = 0; i < SEG; ++i) sat[base + i] = v[i] + off;
    }
    __syncthreads();

    // ---- Phase 2: col prefix, same scheme down columns ----
    if (tid < 4 * HDIM) {
        const int col = tid >> 2, seg = tid & 3;
        const int base = (seg * SEG) * SCOLS + col;
        float v[SEG];
        #pragma unroll
        for (int i = 0; i < SEG; ++i) v[i] = sat[base + i * SCOLS];
        #pragma unroll
        for (int i = 1; i < SEG; ++i) v[i] += v[i - 1];
        float tot = v[SEG - 1];
        float inc = tot;
        float t1 = __shfl_up(inc, 1); if (seg >= 1) inc += t1;
        float t2 = __shfl_up(inc, 2); if (seg >= 2) inc += t2;
        const float off = inc - tot;
        #pragma unroll
        for (int i = 0; i < SEG; ++i) sat[base + i * SCOLS] = v[i] + off;
    }
    __syncthreads();

    // ---- Phase 3: per-pixel fused compute, float4 global loads (NOT hoisted — R3 lesson) ----
    float s_w = 0.0f, s_wb = 0.0f, s_in = 0.0f, s_un = 0.0f, s_mae = 0.0f;

    const int pp[3]    = {1, 7, 15};
    const float inv[3] = {1.0f / 9.0f, 1.0f / 225.0f, 1.0f / 961.0f};

    #pragma unroll
    for (int i = 0; i < 2; ++i) {
        int y  = (tid >> 4) + 32 * i;   // 0..63
        int x4 = (tid & 15) << 2;       // 0,4,...,60
        int gy = ty0 + y, gx = tx0 + x4;
        const float4 m4 = *(const float4*)(mimg + (size_t)gy * W + gx);
        const float4 p4 = *(const float4*)(pimg + (size_t)gy * W + gx);
        const int rc = y + 16;

        #pragma unroll
        for (int q = 0; q < 4; ++q) {
            float m  = (&m4.x)[q];
            float pr = (&p4.x)[q];
            int cc = x4 + q + 16;

            float w = 0.0f;
            #pragma unroll
            for (int j = 0; j < 3; ++j) {
                int r2 = (rc + pp[j]) * SCOLS, r1 = (rc - pp[j] - 1) * SCOLS;
                int c2 = cc + pp[j],           c1 = cc - pp[j] - 1;
                float s = sat[r2 + c2] - sat[r1 + c2]
                        - sat[r2 + c1] + sat[r1 + c1];
                w += fabsf(s * inv[j] - m);
            }
            float weit = 1.0f + 5.0f * w;
            float t    = __expf(-fabsf(pr));                 // shared by bce & sigmoid
            float bce  = fmaxf(pr, 0.0f) - pr * m + __logf(1.0f + t);
            float u    = __builtin_amdgcn_rcpf(1.0f + t);    // 1/(1+e^-|pr|)
            float sig  = (pr >= 0.0f) ? u : 1.0f - u;

            s_w   += weit;
            s_wb  += weit * bce;
            s_in  += sig * m * weit;
            s_un  += (sig + m) * weit;
            s_mae += fabsf(sig - m);
        }
    }

    // ---- Phase 4: block reduction (wave shuffle, then LDS across 8 waves) ----
    #pragma unroll
    for (int off = 32; off > 0; off >>= 1) {
        s_w   += __shfl_down(s_w,   off);
        s_wb  += __shfl_down(s_wb,  off);
        s_in  += __shfl_down(s_in,  off);
        s_un  += __shfl_down(s_un,  off);
        s_mae += __shfl_down(s_mae, off);
    }
    int wave = tid >> 6, lane = tid & 63;
    if (lane == 0) {
        red[wave][0] = s_w;  red[wave][1] = s_wb; red[wave][2] = s_in;
        red[wave][3] = s_un; red[wave][4] = s_mae;
    }
    __syncthreads();
    if (tid == 0) {
        float r0 = 0, r1 = 0, r2 = 0, r3 = 0, r4 = 0;
        #pragma unroll
        for (int wv = 0; wv < 8; ++wv) {
            r0 += red[wv][0]; r1 += red[wv][1]; r2 += red[wv][2];
            r3 += red[wv][3]; r4 += red[wv][4];
        }
        atomicAdd(&acc[b * 5 + 0], r0);
        atomicAdd(&acc[b * 5 + 1], r1);
        atomicAdd(&acc[b * 5 + 2], r2);
        atomicAdd(&acc[b * 5 + 3], r3);
        atomicAdd(&acc[b * 5 + 4], r4);
    }
}

__global__ void adaptive_loss_finalize(const float* __restrict__ acc,
                                       float* __restrict__ out) {
    if (threadIdx.x == 0 && blockIdx.x == 0) {
        float smae = 0.0f;
        for (int b = 0; b < BATCH; ++b) smae += acc[b * 5 + 4];
        float mae = smae / (float)((size_t)BATCH * H * W);
        float tot = 0.0f;
        for (int b = 0; b < BATCH; ++b) {
            float Sw  = acc[b * 5 + 0];
            float Swb = acc[b * 5 + 1];
            float Si  = acc[b * 5 + 2];
            float Su  = acc[b * 5 + 3];
            float wbce = Swb / Sw;
            float wiou = 1.0f - (Si + 1.0f) / (Su - Si + 1.0f);
            float wmae = mae * Sw / (Sw - (float)(H * W));
            tot += 0.7f * (wbce + wiou + wmae);
        }
        out[0] = tot / (float)BATCH;
    }
}

extern "C" void kernel_launch(void* const* d_in, const int* in_sizes, int n_in,
                              void* d_out, int out_size, void* d_ws, size_t ws_size,
                              hipStream_t stream) {
    const float* pred = (const float*)d_in[0];
    const float* mask = (const float*)d_in[1];
    float* acc = (float*)d_ws;

    hipMemsetAsync(acc, 0, ACC_N * sizeof(float), stream);

    dim3 grid(W / TILE, H / TILE, BATCH);
    adaptive_loss_main<<<grid, 512, 0, stream>>>(pred, mask, acc);
    adaptive_loss_finalize<<<1, 64, 0, stream>>>(acc, (float*)d_out);
}

// Round 7
// 261.153 us; speedup vs baseline: 1.3646x; 1.0014x over previous
//
#include <hip/hip_runtime.h>
#include <math.h>

// Problem constants (16 x 1 x 1024 x 1024 fp32 pred/mask -> scalar fp32 loss)
#define BATCH 16
#define H 1024
#define W 1024
#define TILE 64
// Halo layout: halo row hr in [0,96) <-> gy = ty0 - 16 + hr; same for cols.
// Pixel (y,x) of tile <-> halo (y+16, x+16). Windows (p<=15) touch hr,hc in [0,95).
// SAT = inclusive 2D prefix over the 96x96 halo; box = S[r2][c2]-S[r1][c2]-S[r2][c1]+S[r1][c1].
#define HDIM 96
#define SCOLS 97   // stride 97 % 32 == 1 -> scans and lookups land 2-way/bank max (free, m136)
#define SEG  24    // scan segment length: 4 threads per 96-line

// d_ws accumulator layout: acc[b*5 + {0:weit,1:weit*bce,2:inter,3:union,4:mae}]
#define ACC_N (BATCH * 5)

__global__ __launch_bounds__(512, 8)   // 8 waves/EU; LDS caps us at 4 blocks/CU = 32 waves/CU
void adaptive_loss_main(const float* __restrict__ pred,
                        const float* __restrict__ mask,
                        float* __restrict__ acc) {
    __shared__ float sat[HDIM * SCOLS];
    __shared__ float red[8][5];

    const int tid = threadIdx.x;
    const int b   = blockIdx.z;
    const int ty0 = blockIdx.y * TILE;
    const int tx0 = blockIdx.x * TILE;
    const float* mimg = mask + (size_t)b * H * W;
    const float* pimg = pred + (size_t)b * H * W;

    // ---- Fused phase 0+1: load row segment straight from global (6x float4),
    //      prefix in registers, shfl-combine the 4 segment totals (adjacent lanes),
    //      write the row-scanned values to LDS ONCE. No separate load pass, no
    //      intermediate barrier, no LDS round trip. ----
    if (tid < 4 * HDIM) {
        const int row = tid >> 2, seg = tid & 3;
        const int gy  = ty0 - 16 + row;
        const int gx0 = tx0 - 16 + seg * SEG;
        const bool rowok = (gy >= 0) && (gy < H);
        const float* rp = mimg + (size_t)gy * W;

        float v[SEG];
        #pragma unroll
        for (int j = 0; j < 6; ++j) {
            int gx = gx0 + 4 * j;                  // 16B-aligned; chunk fully in or fully out
            float4 t;
            if (rowok && gx >= 0 && gx < W) t = *(const float4*)(rp + gx);
            else                            t = make_float4(0.f, 0.f, 0.f, 0.f);
            v[4 * j + 0] = t.x; v[4 * j + 1] = t.y;
            v[4 * j + 2] = t.z; v[4 * j + 3] = t.w;
        }
        #pragma unroll
        for (int i = 1; i < SEG; ++i) v[i] += v[i - 1];
        float tot = v[SEG - 1];
        float inc = tot;
        float t1 = __shfl_up(inc, 1); if (seg >= 1) inc += t1;
        float t2 = __shfl_up(inc, 2); if (seg >= 2) inc += t2;
        const float off = inc - tot;               // exclusive prefix of segment totals
        const int base = row * SCOLS + seg * SEG;  // banks 2-way max across the wave
        #pragma unroll
        for (int i = 0; i < SEG; ++i) sat[base + i] = v[i] + off;
    }
    __syncthreads();

    // ---- Prefetch phase-3 operands into the col-scan latency window.
    //      Placed AFTER the barrier (so the barrier doesn't drain them) and before
    //      ds_reads (which wait on lgkmcnt, not vmcnt). R3's hazard (loads held
    //      across a ds_write-per-chunk loop) does not apply here. ----
    float4 m4[2], p4[2];
    #pragma unroll
    for (int i = 0; i < 2; ++i) {
        int y  = (tid >> 4) + 32 * i;
        int x4 = (tid & 15) << 2;
        size_t off = (size_t)(ty0 + y) * W + (tx0 + x4);
        m4[i] = *(const float4*)(mimg + off);
        p4[i] = *(const float4*)(pimg + off);
    }

    // ---- Phase 2: col prefix. 4 threads per column, 24 independent reads,
    //      register chain, in-wave shfl segment combine, write back. ----
    if (tid < 4 * HDIM) {
        const int col = tid >> 2, seg = tid & 3;
        const int base = (seg * SEG) * SCOLS + col;
        float v[SEG];
        #pragma unroll
        for (int i = 0; i < SEG; ++i) v[i] = sat[base + i * SCOLS];
        #pragma unroll
        for (int i = 1; i < SEG; ++i) v[i] += v[i - 1];
        float tot = v[SEG - 1];
        float inc = tot;
        float t1 = __shfl_up(inc, 1); if (seg >= 1) inc += t1;
        float t2 = __shfl_up(inc, 2); if (seg >= 2) inc += t2;
        const float off = inc - tot;
        #pragma unroll
        for (int i = 0; i < SEG; ++i) sat[base + i * SCOLS] = v[i] + off;
    }
    __syncthreads();

    // ---- Phase 3: per-pixel fused compute from the SAT (operands already in regs) ----
    float s_w = 0.0f, s_wb = 0.0f, s_in = 0.0f, s_un = 0.0f, s_mae = 0.0f;

    const int pp[3]    = {1, 7, 15};
    const float inv[3] = {1.0f / 9.0f, 1.0f / 225.0f, 1.0f / 961.0f};

    #pragma unroll
    for (int i = 0; i < 2; ++i) {
        int y  = (tid >> 4) + 32 * i;   // 0..63
        int x4 = (tid & 15) << 2;       // 0,4,...,60
        const int rc = y + 16;

        #pragma unroll
        for (int q = 0; q < 4; ++q) {
            float m  = (&m4[i].x)[q];
            float pr = (&p4[i].x)[q];
            int cc = x4 + q + 16;

            float w = 0.0f;
            #pragma unroll
            for (int j = 0; j < 3; ++j) {
                int r2 = (rc + pp[j]) * SCOLS, r1 = (rc - pp[j] - 1) * SCOLS;
                int c2 = cc + pp[j],           c1 = cc - pp[j] - 1;
                float s = sat[r2 + c2] - sat[r1 + c2]
                        - sat[r2 + c1] + sat[r1 + c1];
                w += fabsf(s * inv[j] - m);
            }
            float weit = 1.0f + 5.0f * w;
            float t    = __expf(-fabsf(pr));                 // shared by bce & sigmoid
            float bce  = fmaxf(pr, 0.0f) - pr * m + __logf(1.0f + t);
            float u    = __builtin_amdgcn_rcpf(1.0f + t);    // 1/(1+e^-|pr|)
            float sig  = (pr >= 0.0f) ? u : 1.0f - u;

            s_w   += weit;
            s_wb  += weit * bce;
            s_in  += sig * m * weit;
            s_un  += (sig + m) * weit;
            s_mae += fabsf(sig - m);
        }
    }

    // ---- Phase 4: block reduction (wave shuffle, then LDS across 8 waves) ----
    #pragma unroll
    for (int off = 32; off > 0; off >>= 1) {
        s_w   += __shfl_down(s_w,   off);
        s_wb  += __shfl_down(s_wb,  off);
        s_in  += __shfl_down(s_in,  off);
        s_un  += __shfl_down(s_un,  off);
        s_mae += __shfl_down(s_mae, off);
    }
    int wave = tid >> 6, lane = tid & 63;
    if (lane == 0) {
        red[wave][0] = s_w;  red[wave][1] = s_wb; red[wave][2] = s_in;
        red[wave][3] = s_un; red[wave][4] = s_mae;
    }
    __syncthreads();
    if (tid == 0) {
        float r0 = 0, r1 = 0, r2 = 0, r3 = 0, r4 = 0;
        #pragma unroll
        for (int wv = 0; wv < 8; ++wv) {
            r0 += red[wv][0]; r1 += red[wv][1]; r2 += red[wv][2];
            r3 += red[wv][3]; r4 += red[wv][4];
        }
        atomicAdd(&acc[b * 5 + 0], r0);
        atomicAdd(&acc[b * 5 + 1], r1);
        atomicAdd(&acc[b * 5 + 2], r2);
        atomicAdd(&acc[b * 5 + 3], r3);
        atomicAdd(&acc[b * 5 + 4], r4);
    }
}

__global__ void adaptive_loss_finalize(const float* __restrict__ acc,
                                       float* __restrict__ out) {
    if (threadIdx.x == 0 && blockIdx.x == 0) {
        float smae = 0.0f;
        for (int b = 0; b < BATCH; ++b) smae += acc[b * 5 + 4];
        float mae = smae / (float)((size_t)BATCH * H * W);
        float tot = 0.0f;
        for (int b = 0; b < BATCH; ++b) {
            float Sw  = acc[b * 5 + 0];
            float Swb = acc[b * 5 + 1];
            float Si  = acc[b * 5 + 2];
            float Su  = acc[b * 5 + 3];
            float wbce = Swb / Sw;
            float wiou = 1.0f - (Si + 1.0f) / (Su - Si + 1.0f);
            float wmae = mae * Sw / (Sw - (float)(H * W));
            tot += 0.7f * (wbce + wiou + wmae);
        }
        out[0] = tot / (float)BATCH;
    }
}

extern "C" void kernel_launch(void* const* d_in, const int* in_sizes, int n_in,
                              void* d_out, int out_size, void* d_ws, size_t ws_size,
                              hipStream_t stream) {
    const float* pred = (const float*)d_in[0];
    const float* mask = (const float*)d_in[1];
    float* acc = (float*)d_ws;

    hipMemsetAsync(acc, 0, ACC_N * sizeof(float), stream);

    dim3 grid(W / TILE, H / TILE, BATCH);
    adaptive_loss_main<<<grid, 512, 0, stream>>>(pred, mask, acc);
    adaptive_loss_finalize<<<1, 64, 0, stream>>>(acc, (float*)d_out);
}